// Round 6
// baseline (265.838 us; speedup 1.0000x reference)
//
#include <hip/hip_runtime.h>

// B=4, S=1024, E=1024, H=16, D=64.  All MFMA in bf16 (16x16x32), fp32 accum.
// qk  : [4096][2048] bf16  (Q|K), Q pre-scaled by 0.125*log2(e)
// vt  : [64 bh][64 d][1024 t] bf16  (V transposed, built in GEMM epilogue)
// ml  : invl/16 (float) per (b,h,row) -- softmax uses shift 0 (no max tracking)

typedef unsigned short u16;
using s16x8 = __attribute__((ext_vector_type(8))) short;   // 8 bf16 = 4 VGPR
using f32x4 = __attribute__((ext_vector_type(4))) float;   // MFMA C/D
using u16x4 = __attribute__((ext_vector_type(4))) unsigned short;

#define AS1 __attribute__((address_space(1)))
#define AS3 __attribute__((address_space(3)))

#define QSCALE 0.1803368801111204f   // 0.125 * log2(e)

__device__ __forceinline__ u16 f2bf(float f) {
    unsigned u = __float_as_uint(f);
    u += 0x7fffu + ((u >> 16) & 1u);   // RTN-even
    return (u16)(u >> 16);
}

// ---------------- fused fp32->bf16 converts + ctxvec init ----------------
// f4 ranges: X 1048576 | Wqkv 786432 | Wout 262144  (sum = 8192*256 exactly)
__global__ void k_prep(const float* __restrict__ X, const float* __restrict__ W1,
                       const float* __restrict__ W2, const float* __restrict__ bout,
                       u16* __restrict__ Xb, u16* __restrict__ W1b, u16* __restrict__ W2b,
                       float* __restrict__ out) {
    int i = blockIdx.x * blockDim.x + threadIdx.x;
    const float* src; u16* dst; int off;
    if (i < 1048576)       { src = X;  dst = Xb;  off = i; }
    else if (i < 1835008)  { src = W1; dst = W1b; off = i - 1048576; }
    else                   { src = W2; dst = W2b; off = i - 1835008; }
    float4 v = reinterpret_cast<const float4*>(src)[off];
    u16x4 o = { f2bf(v.x), f2bf(v.y), f2bf(v.z), f2bf(v.w) };
    reinterpret_cast<u16x4*>(dst)[off] = o;
    if (i < 4096) out[i] = bout[i & 1023];
}

// ---------------- 128x128 BT GEMM (m97 + T2 swizzle + XCD swizzle + LDS dbuf) ----------------
// Pipelined: sync; STAGE(k+1 -> buf^1); compute(buf).  One barrier per K-step.
// MODE 1 splits K by blockIdx.z (partial colsums additive into atomicAdd).
template<int MODE>
__global__ __launch_bounds__(256) void k_gemm_bt(
    const u16* __restrict__ A, const u16* __restrict__ B,
    const float* __restrict__ bias, u16* __restrict__ C,
    u16* __restrict__ vt, float* __restrict__ outvec) {
    const int K = 1024;
    constexpr int KSLICE = (MODE == 0) ? 1024 : 256;
    const int nbx = gridDim.x;
    const int nwg = nbx * gridDim.y;
    const int bid = blockIdx.y * nbx + blockIdx.x;
    const int per = nwg >> 3;
    const int swz = (bid & 7) * per + (bid >> 3);
    const int n0 = (swz % nbx) * 128, m0 = (swz / nbx) * 128;
    const int kbeg = blockIdx.z * KSLICE, kend = kbeg + KSLICE;
    const int tid = threadIdx.x, lane = tid & 63, w = tid >> 6;
    const int wm = w >> 1, wn = w & 1;
    const int g = lane >> 4, l15 = lane & 15;
    __shared__ __attribute__((aligned(16))) u16 As[2][128 * 64];
    __shared__ __attribute__((aligned(16))) u16 Bs[2][128 * 64];

    f32x4 acc[4][4];
    #pragma unroll
    for (int mi = 0; mi < 4; ++mi)
        #pragma unroll
        for (int nj = 0; nj < 4; ++nj) acc[mi][nj] = (f32x4){0.f, 0.f, 0.f, 0.f};

    auto STAGE = [&](int k0, int sb) {
        #pragma unroll
        for (int r = 0; r < 4; ++r) {
            int c = tid + r * 256;
            int row = c >> 3, j = c & 7;
            int js = j ^ (row & 7);            // pre-swizzled source chunk (rule #21)
            __builtin_amdgcn_global_load_lds(
                (AS1 const void*)(A + (size_t)(m0 + row) * K + k0 + js * 8),
                (AS3 void*)(&As[sb][c * 8]), 16, 0, 0);
            __builtin_amdgcn_global_load_lds(
                (AS1 const void*)(B + (size_t)(n0 + row) * K + k0 + js * 8),
                (AS3 void*)(&Bs[sb][c * 8]), 16, 0, 0);
        }
    };

    STAGE(kbeg, 0);
    int buf = 0;
    for (int k0 = kbeg; k0 < kend; k0 += 64) {
        __syncthreads();                       // buf ready; buf^1 free (prev compute done)
        if (k0 + 64 < kend) STAGE(k0 + 64, buf ^ 1);
        #pragma unroll
        for (int kk = 0; kk < 64; kk += 32) {
            const int cx0 = (((kk >> 3) + g) ^ (l15 & 7)) * 8;   // swizzled read chunk
            s16x8 av[4], bv[4];
            #pragma unroll
            for (int mi = 0; mi < 4; ++mi)
                av[mi] = *reinterpret_cast<const s16x8*>(
                    &As[buf][(wm * 64 + mi * 16 + l15) * 64 + cx0]);
            #pragma unroll
            for (int nj = 0; nj < 4; ++nj)
                bv[nj] = *reinterpret_cast<const s16x8*>(
                    &Bs[buf][(wn * 64 + nj * 16 + l15) * 64 + cx0]);
            #pragma unroll
            for (int mi = 0; mi < 4; ++mi)
                #pragma unroll
                for (int nj = 0; nj < 4; ++nj)
                    acc[mi][nj] = __builtin_amdgcn_mfma_f32_16x16x32_bf16(av[mi], bv[nj], acc[mi][nj], 0, 0, 0);
        }
        buf ^= 1;
    }

    if constexpr (MODE == 0) {
        #pragma unroll
        for (int nj = 0; nj < 4; ++nj) {
            int n = n0 + wn * 64 + nj * 16 + l15;
            float scale = (n < 1024) ? QSCALE : 1.0f;
            float bvs = bias[n] * scale;
            if (n < 2048) {
                #pragma unroll
                for (int mi = 0; mi < 4; ++mi)
                    #pragma unroll
                    for (int i = 0; i < 4; ++i) {
                        int m = m0 + wm * 64 + mi * 16 + g * 4 + i;
                        C[(size_t)m * 2048 + n] = f2bf(acc[mi][nj][i] * scale + bvs);
                    }
            } else {
                int hd = n - 2048;                       // h*64 + d
                #pragma unroll
                for (int mi = 0; mi < 4; ++mi)
                    #pragma unroll
                    for (int i = 0; i < 4; ++i) {
                        int m = m0 + wm * 64 + mi * 16 + g * 4 + i;
                        int b = m >> 10, t = m & 1023;
                        vt[((size_t)(b * 16 + (hd >> 6)) * 64 + (hd & 63)) * 1024 + t] =
                            f2bf(acc[mi][nj][i] + bvs);
                    }
            }
        }
    } else {
        int b = m0 >> 10;
        #pragma unroll
        for (int nj = 0; nj < 4; ++nj) {
            float s = 0.f;
            #pragma unroll
            for (int mi = 0; mi < 4; ++mi)
                #pragma unroll
                for (int i = 0; i < 4; ++i) s += acc[mi][nj][i];
            s += __shfl_xor(s, 16);
            s += __shfl_xor(s, 32);
            if (g == 0) {
                int n = n0 + wn * 64 + nj * 16 + l15;
                atomicAdd(&outvec[b * 1024 + n], s * (1.0f / 1024.0f));
            }
        }
    }
}

// ---------------- flash attention: per (b, h, 64-row q-tile) ----------------
__global__ __launch_bounds__(256, 4) void k_flash(const u16* __restrict__ qk,
                                                  const u16* __restrict__ vt,
                                                  u16* __restrict__ ctx,
                                                  float* __restrict__ ml) {
    const int id = blockIdx.x + 16 * (blockIdx.y + 16 * blockIdx.z);
    const int x = id & 7, kq = id >> 3;
    const int gbh = x * 8 + (kq >> 4);
    const int qt = kq & 15;
    const int b = gbh >> 4, h = gbh & 15;
    const int q0 = qt * 64;
    const int tid = threadIdx.x, lane = tid & 63, w = tid >> 6;
    const int g = lane >> 4, l15 = lane & 15;
    __shared__ __attribute__((aligned(16))) u16 Ks[2][64 * 64];
    __shared__ __attribute__((aligned(16))) u16 Vt[2][64 * 64];
    __shared__ __attribute__((aligned(16))) u16 Ps[4][16 * 64];

    const size_t rowQ = (size_t)(b * 1024 + q0 + w * 16 + l15) * 2048 + h * 64;
    const s16x8 qa0 = *reinterpret_cast<const s16x8*>(qk + rowQ + g * 8);
    const s16x8 qa1 = *reinterpret_cast<const s16x8*>(qk + rowQ + 32 + g * 8);

    const int cA = tid, cB = tid + 256;
    const int rowA = cA >> 3, jA = cA & 7, rowB = cB >> 3, jB = cB & 7;
    const u16* kbase0 = qk + (size_t)(b * 1024) * 2048 + 1024 + h * 64;
    const u16* vtb = vt + (size_t)(b * 16 + h) * 65536;

    __builtin_amdgcn_global_load_lds((AS1 const void*)(kbase0 + (size_t)rowA * 2048 + ((jA ^ (rowA & 7)) * 8)),
                                     (AS3 void*)(&Ks[0][cA * 8]), 16, 0, 0);
    __builtin_amdgcn_global_load_lds((AS1 const void*)(kbase0 + (size_t)rowB * 2048 + ((jB ^ (rowB & 7)) * 8)),
                                     (AS3 void*)(&Ks[0][cB * 8]), 16, 0, 0);
    __builtin_amdgcn_global_load_lds((AS1 const void*)(vtb + (size_t)rowA * 1024 + ((jA ^ (rowA & 7)) * 8)),
                                     (AS3 void*)(&Vt[0][cA * 8]), 16, 0, 0);
    __builtin_amdgcn_global_load_lds((AS1 const void*)(vtb + (size_t)rowB * 1024 + ((jB ^ (rowB & 7)) * 8)),
                                     (AS3 void*)(&Vt[0][cB * 8]), 16, 0, 0);

    f32x4 ctxa[4];
    #pragma unroll
    for (int nj = 0; nj < 4; ++nj) ctxa[nj] = (f32x4){0.f, 0.f, 0.f, 0.f};
    float lsum = 0.f;

    int buf = 0;
    for (int kt = 0; kt < 16; ++kt) {
        __syncthreads();
        if (kt < 15) {
            int t0n = (kt + 1) * 64;
            const u16* kbase = kbase0 + (size_t)t0n * 2048;
            __builtin_amdgcn_global_load_lds((AS1 const void*)(kbase + (size_t)rowA * 2048 + ((jA ^ (rowA & 7)) * 8)),
                                             (AS3 void*)(&Ks[buf ^ 1][cA * 8]), 16, 0, 0);
            __builtin_amdgcn_global_load_lds((AS1 const void*)(kbase + (size_t)rowB * 2048 + ((jB ^ (rowB & 7)) * 8)),
                                             (AS3 void*)(&Ks[buf ^ 1][cB * 8]), 16, 0, 0);
            const u16* vbase = vtb + t0n;
            __builtin_amdgcn_global_load_lds((AS1 const void*)(vbase + (size_t)rowA * 1024 + ((jA ^ (rowA & 7)) * 8)),
                                             (AS3 void*)(&Vt[buf ^ 1][cA * 8]), 16, 0, 0);
            __builtin_amdgcn_global_load_lds((AS1 const void*)(vbase + (size_t)rowB * 1024 + ((jB ^ (rowB & 7)) * 8)),
                                             (AS3 void*)(&Vt[buf ^ 1][cB * 8]), 16, 0, 0);
        }

        f32x4 sc[4];
        #pragma unroll
        for (int tj = 0; tj < 4; ++tj) sc[tj] = (f32x4){0.f, 0.f, 0.f, 0.f};
        #pragma unroll
        for (int kk = 0; kk < 64; kk += 32) {
            s16x8 qa = kk ? qa1 : qa0;
            #pragma unroll
            for (int tj = 0; tj < 4; ++tj) {
                int trow = tj * 16 + l15;
                s16x8 kb = *reinterpret_cast<const s16x8*>(
                    &Ks[buf][trow * 64 + ((((kk >> 3) + g) ^ (trow & 7)) * 8)]);
                sc[tj] = __builtin_amdgcn_mfma_f32_16x16x32_bf16(kb, qa, sc[tj], 0, 0, 0);
            }
        }

        #pragma unroll
        for (int tj = 0; tj < 4; ++tj)
            #pragma unroll
            for (int i = 0; i < 4; ++i) {
                float p = exp2f(fminf(sc[tj][i], 60.f));
                sc[tj][i] = p;
                lsum += p;
            }

        #pragma unroll
        for (int tj = 0; tj < 4; ++tj) {
            u16x4 pk = { f2bf(sc[tj][0]), f2bf(sc[tj][1]), f2bf(sc[tj][2]), f2bf(sc[tj][3]) };
            *reinterpret_cast<u16x4*>(
                &Ps[w][l15 * 64 + (((tj * 2 + (g >> 1)) ^ (l15 & 7)) * 8) + (g & 1) * 4]) = pk;
        }

        #pragma unroll
        for (int kk = 0; kk < 64; kk += 32) {
            s16x8 pa = *reinterpret_cast<const s16x8*>(
                &Ps[w][l15 * 64 + ((((kk >> 3) + g) ^ (l15 & 7)) * 8)]);
            #pragma unroll
            for (int nj = 0; nj < 4; ++nj) {
                int d = nj * 16 + l15;
                s16x8 vb = *reinterpret_cast<const s16x8*>(
                    &Vt[buf][d * 64 + ((((kk >> 3) + g) ^ (d & 7)) * 8)]);
                ctxa[nj] = __builtin_amdgcn_mfma_f32_16x16x32_bf16(pa, vb, ctxa[nj], 0, 0, 0);
            }
        }
        buf ^= 1;
    }

    lsum += __shfl_xor(lsum, 16);
    lsum += __shfl_xor(lsum, 32);
    float invl = 1.0f / lsum;
    if (g == 0)
        ml[(size_t)(b * 16 + h) * 1024 + q0 + w * 16 + l15] = invl * 0.0625f;

    float invl_i[4];
    #pragma unroll
    for (int i = 0; i < 4; ++i) invl_i[i] = __shfl(invl, g * 4 + i);

    #pragma unroll
    for (int i = 0; i < 4; ++i) {
        int row = q0 + w * 16 + g * 4 + i;
        #pragma unroll
        for (int nj = 0; nj < 4; ++nj) {
            int d = nj * 16 + l15;
            ctx[(size_t)(b * 1024 + row) * 1024 + h * 64 + d] = f2bf(ctxa[nj][i] * invl_i[i]);
        }
    }
}

// ---------------- attn_weights: mean over heads, 2 heads per barrier ----------------
__global__ __launch_bounds__(256, 4) void k_attnw(const u16* __restrict__ qk,
                                                  const float* __restrict__ ml,
                                                  float* __restrict__ attnw) {
    const int tt = blockIdx.x, st = blockIdx.y, b = blockIdx.z;
    const int s0 = st * 64, t0 = tt * 64;
    const int tid = threadIdx.x, lane = tid & 63, w = tid >> 6;
    const int g = lane >> 4, l15 = lane & 15;
    __shared__ __attribute__((aligned(16))) u16 Ks[2][2][64 * 64];  // [buf][head-in-pair]
    __shared__ float mls[16][64];   // invl/16 per (h,row)

    #pragma unroll
    for (int r = 0; r < 4; ++r) {
        int idx = tid + r * 256;
        int hh = idx >> 6, row = idx & 63;
        mls[hh][row] = ml[(size_t)(b * 16 + hh) * 1024 + s0 + row];
    }

    const int cA = tid, cB = tid + 256;
    const int rowA = cA >> 3, jA = cA & 7, rowB = cB >> 3, jB = cB & 7;
    const u16* kbase = qk + (size_t)(b * 1024 + t0) * 2048 + 1024;
    const size_t rowQbase = (size_t)(b * 1024 + s0 + w * 16 + l15) * 2048;

    auto KSTAGE = [&](int h, int sb, int hi) {
        const u16* kb2 = kbase + h * 64;
        __builtin_amdgcn_global_load_lds((AS1 const void*)(kb2 + (size_t)rowA * 2048 + ((jA ^ (rowA & 7)) * 8)),
                                         (AS3 void*)(&Ks[sb][hi][cA * 8]), 16, 0, 0);
        __builtin_amdgcn_global_load_lds((AS1 const void*)(kb2 + (size_t)rowB * 2048 + ((jB ^ (rowB & 7)) * 8)),
                                         (AS3 void*)(&Ks[sb][hi][cB * 8]), 16, 0, 0);
    };

    KSTAGE(0, 0, 0);
    KSTAGE(1, 0, 1);
    s16x8 qc[2][2], qn[2][2];
    #pragma unroll
    for (int hi = 0; hi < 2; ++hi) {
        qc[hi][0] = *reinterpret_cast<const s16x8*>(qk + rowQbase + hi * 64 + g * 8);
        qc[hi][1] = *reinterpret_cast<const s16x8*>(qk + rowQbase + hi * 64 + 32 + g * 8);
    }

    f32x4 acc[4];
    #pragma unroll
    for (int tj = 0; tj < 4; ++tj) acc[tj] = (f32x4){0.f, 0.f, 0.f, 0.f};

    int buf = 0;
    for (int hp = 0; hp < 16; hp += 2) {
        __syncthreads();
        if (hp < 14) {
            KSTAGE(hp + 2, buf ^ 1, 0);
            KSTAGE(hp + 3, buf ^ 1, 1);
            #pragma unroll
            for (int hi = 0; hi < 2; ++hi) {
                qn[hi][0] = *reinterpret_cast<const s16x8*>(qk + rowQbase + (hp + 2 + hi) * 64 + g * 8);
                qn[hi][1] = *reinterpret_cast<const s16x8*>(qk + rowQbase + (hp + 2 + hi) * 64 + 32 + g * 8);
            }
        }

        #pragma unroll
        for (int hi = 0; hi < 2; ++hi) {
            f32x4 sc[4];
            #pragma unroll
            for (int tj = 0; tj < 4; ++tj) sc[tj] = (f32x4){0.f, 0.f, 0.f, 0.f};
            #pragma unroll
            for (int kk = 0; kk < 64; kk += 32) {
                s16x8 qa = kk ? qc[hi][1] : qc[hi][0];
                #pragma unroll
                for (int tj = 0; tj < 4; ++tj) {
                    int trow = tj * 16 + l15;
                    s16x8 kb = *reinterpret_cast<const s16x8*>(
                        &Ks[buf][hi][trow * 64 + ((((kk >> 3) + g) ^ (trow & 7)) * 8)]);
                    sc[tj] = __builtin_amdgcn_mfma_f32_16x16x32_bf16(qa, kb, sc[tj], 0, 0, 0);
                }
            }
            #pragma unroll
            for (int i = 0; i < 4; ++i) {
                int row = w * 16 + g * 4 + i;
                float M = mls[hp + hi][row];
                #pragma unroll
                for (int tj = 0; tj < 4; ++tj)
                    acc[tj][i] += exp2f(fminf(sc[tj][i], 60.f)) * M;
            }
        }
        #pragma unroll
        for (int hi = 0; hi < 2; ++hi) { qc[hi][0] = qn[hi][0]; qc[hi][1] = qn[hi][1]; }
        buf ^= 1;
    }

    #pragma unroll
    for (int i = 0; i < 4; ++i) {
        int row = s0 + w * 16 + g * 4 + i;
        #pragma unroll
        for (int tj = 0; tj < 4; ++tj)
            attnw[(size_t)(b * 1024 + row) * 1024 + t0 + tj * 16 + l15] = acc[tj][i];
    }
}

// ---------------- launch ----------------
extern "C" void kernel_launch(void* const* d_in, const int* in_sizes, int n_in,
                              void* d_out, int out_size, void* d_ws, size_t ws_size,
                              hipStream_t stream) {
    const float* lstm = (const float*)d_in[0];   // [4,1024,1024]
    const float* wqkv = (const float*)d_in[1];   // [3072,1024]
    const float* bqkv = (const float*)d_in[2];   // [3072]
    const float* wout = (const float*)d_in[3];   // [1024,1024]
    const float* bout = (const float*)d_in[4];   // [1024]
    float* out = (float*)d_out;                  // [4096 ctxvec | 4*1024*1024 attn]

    char* ws = (char*)d_ws;
    u16*   Xbf   = (u16*)(ws);                          // 8 MiB
    u16*   Wqkvb = (u16*)(ws + 8u  * 1024 * 1024);      // 6 MiB
    u16*   Woutb = (u16*)(ws + 14u * 1024 * 1024);      // 2 MiB
    u16*   qkbuf = (u16*)(ws + 16u * 1024 * 1024);      // 16 MiB  [4096][2048]
    u16*   ctx   = (u16*)(ws + 32u * 1024 * 1024);      // 8 MiB
    u16*   vtg   = (u16*)(ws + 40u * 1024 * 1024);      // 8 MiB   [64][64][1024]
    float* ml    = (float*)(ws + 48u * 1024 * 1024);    // 256 KiB (invl/16)

    k_prep<<<8192, 256, 0, stream>>>(lstm, wqkv, wout, bout, Xbf, Wqkvb, Woutb, out);

    k_gemm_bt<0><<<dim3(24, 32), 256, 0, stream>>>(Xbf, Wqkvb, bqkv, qkbuf, vtg, nullptr);
    k_flash<<<dim3(16, 16, 4), 256, 0, stream>>>(qkbuf, vtg, ctx, ml);
    k_attnw<<<dim3(16, 16, 4), 256, 0, stream>>>(qkbuf, ml, out + 4096);
    k_gemm_bt<1><<<dim3(8, 32, 4), 256, 0, stream>>>(ctx, Woutb, nullptr, nullptr, nullptr, out);
}

// Round 7
// 135.071 us; speedup vs baseline: 1.9681x; 1.9681x over previous
//
#include <hip/hip_runtime.h>

// B=4, S=1024, E=1024, H=16, D=64.  All MFMA in bf16 (16x16x32), fp32 accum.
// qk  : [4096][2048] bf16  (Q|K), Q pre-scaled by 0.125*log2(e)
// vt  : [64 bh][64 d][1024 t] bf16  (V transposed, built in GEMM epilogue)
// ml  : invl/16 (float) per (b,h,row) -- softmax uses shift 0 (no max tracking)

typedef unsigned short u16;
using s16x8 = __attribute__((ext_vector_type(8))) short;   // 8 bf16 = 4 VGPR
using f32x4 = __attribute__((ext_vector_type(4))) float;   // MFMA C/D
using u16x4 = __attribute__((ext_vector_type(4))) unsigned short;

#define AS1 __attribute__((address_space(1)))
#define AS3 __attribute__((address_space(3)))

#define QSCALE 0.1803368801111204f   // 0.125 * log2(e)

__device__ __forceinline__ u16 f2bf(float f) {
    unsigned u = __float_as_uint(f);
    u += 0x7fffu + ((u >> 16) & 1u);   // RTN-even
    return (u16)(u >> 16);
}

// ---------------- fused fp32->bf16 converts + ctxvec init ----------------
// f4 ranges: X 1048576 | Wqkv 786432 | Wout 262144  (sum = 8192*256 exactly)
__global__ void k_prep(const float* __restrict__ X, const float* __restrict__ W1,
                       const float* __restrict__ W2, const float* __restrict__ bout,
                       u16* __restrict__ Xb, u16* __restrict__ W1b, u16* __restrict__ W2b,
                       float* __restrict__ out) {
    int i = blockIdx.x * blockDim.x + threadIdx.x;
    const float* src; u16* dst; int off;
    if (i < 1048576)       { src = X;  dst = Xb;  off = i; }
    else if (i < 1835008)  { src = W1; dst = W1b; off = i - 1048576; }
    else                   { src = W2; dst = W2b; off = i - 1835008; }
    float4 v = reinterpret_cast<const float4*>(src)[off];
    u16x4 o = { f2bf(v.x), f2bf(v.y), f2bf(v.z), f2bf(v.w) };
    reinterpret_cast<u16x4*>(dst)[off] = o;
    if (i < 4096) out[i] = bout[i & 1023];
}

// ---------------- 128x128 BT GEMM (m97 + T2 swizzle + XCD swizzle + LDS dbuf) ----------------
template<int MODE>
__global__ __launch_bounds__(256) void k_gemm_bt(
    const u16* __restrict__ A, const u16* __restrict__ B,
    const float* __restrict__ bias, u16* __restrict__ C,
    u16* __restrict__ vt, float* __restrict__ outvec) {
    const int K = 1024;
    constexpr int KSLICE = (MODE == 0) ? 1024 : 256;
    const int nbx = gridDim.x;
    const int nwg = nbx * gridDim.y;
    const int bid = blockIdx.y * nbx + blockIdx.x;
    const int per = nwg >> 3;
    const int swz = (bid & 7) * per + (bid >> 3);
    const int n0 = (swz % nbx) * 128, m0 = (swz / nbx) * 128;
    const int kbeg = blockIdx.z * KSLICE, kend = kbeg + KSLICE;
    const int tid = threadIdx.x, lane = tid & 63, w = tid >> 6;
    const int wm = w >> 1, wn = w & 1;
    const int g = lane >> 4, l15 = lane & 15;
    __shared__ __attribute__((aligned(16))) u16 As[2][128 * 64];
    __shared__ __attribute__((aligned(16))) u16 Bs[2][128 * 64];

    f32x4 acc[4][4];
    #pragma unroll
    for (int mi = 0; mi < 4; ++mi)
        #pragma unroll
        for (int nj = 0; nj < 4; ++nj) acc[mi][nj] = (f32x4){0.f, 0.f, 0.f, 0.f};

    auto STAGE = [&](int k0, int sb) {
        #pragma unroll
        for (int r = 0; r < 4; ++r) {
            int c = tid + r * 256;
            int row = c >> 3, j = c & 7;
            int js = j ^ (row & 7);            // pre-swizzled source chunk (rule #21)
            __builtin_amdgcn_global_load_lds(
                (AS1 const void*)(A + (size_t)(m0 + row) * K + k0 + js * 8),
                (AS3 void*)(&As[sb][c * 8]), 16, 0, 0);
            __builtin_amdgcn_global_load_lds(
                (AS1 const void*)(B + (size_t)(n0 + row) * K + k0 + js * 8),
                (AS3 void*)(&Bs[sb][c * 8]), 16, 0, 0);
        }
    };

    STAGE(kbeg, 0);
    int buf = 0;
    for (int k0 = kbeg; k0 < kend; k0 += 64) {
        __syncthreads();                       // buf ready; buf^1 free (prev compute done)
        if (k0 + 64 < kend) STAGE(k0 + 64, buf ^ 1);
        #pragma unroll
        for (int kk = 0; kk < 64; kk += 32) {
            const int cx0 = (((kk >> 3) + g) ^ (l15 & 7)) * 8;   // swizzled read chunk
            s16x8 av[4], bv[4];
            #pragma unroll
            for (int mi = 0; mi < 4; ++mi)
                av[mi] = *reinterpret_cast<const s16x8*>(
                    &As[buf][(wm * 64 + mi * 16 + l15) * 64 + cx0]);
            #pragma unroll
            for (int nj = 0; nj < 4; ++nj)
                bv[nj] = *reinterpret_cast<const s16x8*>(
                    &Bs[buf][(wn * 64 + nj * 16 + l15) * 64 + cx0]);
            #pragma unroll
            for (int mi = 0; mi < 4; ++mi)
                #pragma unroll
                for (int nj = 0; nj < 4; ++nj)
                    acc[mi][nj] = __builtin_amdgcn_mfma_f32_16x16x32_bf16(av[mi], bv[nj], acc[mi][nj], 0, 0, 0);
        }
        buf ^= 1;
    }

    if constexpr (MODE == 0) {
        #pragma unroll
        for (int nj = 0; nj < 4; ++nj) {
            int n = n0 + wn * 64 + nj * 16 + l15;
            float scale = (n < 1024) ? QSCALE : 1.0f;
            float bvs = bias[n] * scale;
            if (n < 2048) {
                #pragma unroll
                for (int mi = 0; mi < 4; ++mi)
                    #pragma unroll
                    for (int i = 0; i < 4; ++i) {
                        int m = m0 + wm * 64 + mi * 16 + g * 4 + i;
                        C[(size_t)m * 2048 + n] = f2bf(acc[mi][nj][i] * scale + bvs);
                    }
            } else {
                int hd = n - 2048;                       // h*64 + d
                #pragma unroll
                for (int mi = 0; mi < 4; ++mi)
                    #pragma unroll
                    for (int i = 0; i < 4; ++i) {
                        int m = m0 + wm * 64 + mi * 16 + g * 4 + i;
                        int b = m >> 10, t = m & 1023;
                        vt[((size_t)(b * 16 + (hd >> 6)) * 64 + (hd & 63)) * 1024 + t] =
                            f2bf(acc[mi][nj][i] + bvs);
                    }
            }
        }
    } else {
        int b = m0 >> 10;
        #pragma unroll
        for (int nj = 0; nj < 4; ++nj) {
            float s = 0.f;
            #pragma unroll
            for (int mi = 0; mi < 4; ++mi)
                #pragma unroll
                for (int i = 0; i < 4; ++i) s += acc[mi][nj][i];
            s += __shfl_xor(s, 16);
            s += __shfl_xor(s, 32);
            if (g == 0) {
                int n = n0 + wn * 64 + nj * 16 + l15;
                atomicAdd(&outvec[b * 1024 + n], s * (1.0f / 1024.0f));
            }
        }
    }
}

// ---------------- flash attention: per (b, h, 64-row q-tile) ----------------
__global__ __launch_bounds__(256, 4) void k_flash(const u16* __restrict__ qk,
                                                  const u16* __restrict__ vt,
                                                  u16* __restrict__ ctx,
                                                  float* __restrict__ ml) {
    const int id = blockIdx.x + 16 * (blockIdx.y + 16 * blockIdx.z);
    const int x = id & 7, kq = id >> 3;
    const int gbh = x * 8 + (kq >> 4);
    const int qt = kq & 15;
    const int b = gbh >> 4, h = gbh & 15;
    const int q0 = qt * 64;
    const int tid = threadIdx.x, lane = tid & 63, w = tid >> 6;
    const int g = lane >> 4, l15 = lane & 15;
    __shared__ __attribute__((aligned(16))) u16 Ks[2][64 * 64];
    __shared__ __attribute__((aligned(16))) u16 Vt[2][64 * 64];
    __shared__ __attribute__((aligned(16))) u16 Ps[4][16 * 64];

    const size_t rowQ = (size_t)(b * 1024 + q0 + w * 16 + l15) * 2048 + h * 64;
    const s16x8 qa0 = *reinterpret_cast<const s16x8*>(qk + rowQ + g * 8);
    const s16x8 qa1 = *reinterpret_cast<const s16x8*>(qk + rowQ + 32 + g * 8);

    const int cA = tid, cB = tid + 256;
    const int rowA = cA >> 3, jA = cA & 7, rowB = cB >> 3, jB = cB & 7;
    const u16* kbase0 = qk + (size_t)(b * 1024) * 2048 + 1024 + h * 64;
    const u16* vtb = vt + (size_t)(b * 16 + h) * 65536;

    __builtin_amdgcn_global_load_lds((AS1 const void*)(kbase0 + (size_t)rowA * 2048 + ((jA ^ (rowA & 7)) * 8)),
                                     (AS3 void*)(&Ks[0][cA * 8]), 16, 0, 0);
    __builtin_amdgcn_global_load_lds((AS1 const void*)(kbase0 + (size_t)rowB * 2048 + ((jB ^ (rowB & 7)) * 8)),
                                     (AS3 void*)(&Ks[0][cB * 8]), 16, 0, 0);
    __builtin_amdgcn_global_load_lds((AS1 const void*)(vtb + (size_t)rowA * 1024 + ((jA ^ (rowA & 7)) * 8)),
                                     (AS3 void*)(&Vt[0][cA * 8]), 16, 0, 0);
    __builtin_amdgcn_global_load_lds((AS1 const void*)(vtb + (size_t)rowB * 1024 + ((jB ^ (rowB & 7)) * 8)),
                                     (AS3 void*)(&Vt[0][cB * 8]), 16, 0, 0);

    f32x4 ctxa[4];
    #pragma unroll
    for (int nj = 0; nj < 4; ++nj) ctxa[nj] = (f32x4){0.f, 0.f, 0.f, 0.f};
    float lsum = 0.f;

    int buf = 0;
    for (int kt = 0; kt < 16; ++kt) {
        __syncthreads();
        if (kt < 15) {
            int t0n = (kt + 1) * 64;
            const u16* kbase = kbase0 + (size_t)t0n * 2048;
            __builtin_amdgcn_global_load_lds((AS1 const void*)(kbase + (size_t)rowA * 2048 + ((jA ^ (rowA & 7)) * 8)),
                                             (AS3 void*)(&Ks[buf ^ 1][cA * 8]), 16, 0, 0);
            __builtin_amdgcn_global_load_lds((AS1 const void*)(kbase + (size_t)rowB * 2048 + ((jB ^ (rowB & 7)) * 8)),
                                             (AS3 void*)(&Ks[buf ^ 1][cB * 8]), 16, 0, 0);
            const u16* vbase = vtb + t0n;
            __builtin_amdgcn_global_load_lds((AS1 const void*)(vbase + (size_t)rowA * 1024 + ((jA ^ (rowA & 7)) * 8)),
                                             (AS3 void*)(&Vt[buf ^ 1][cA * 8]), 16, 0, 0);
            __builtin_amdgcn_global_load_lds((AS1 const void*)(vbase + (size_t)rowB * 1024 + ((jB ^ (rowB & 7)) * 8)),
                                             (AS3 void*)(&Vt[buf ^ 1][cB * 8]), 16, 0, 0);
        }

        f32x4 sc[4];
        #pragma unroll
        for (int tj = 0; tj < 4; ++tj) sc[tj] = (f32x4){0.f, 0.f, 0.f, 0.f};
        #pragma unroll
        for (int kk = 0; kk < 64; kk += 32) {
            s16x8 qa = kk ? qa1 : qa0;
            #pragma unroll
            for (int tj = 0; tj < 4; ++tj) {
                int trow = tj * 16 + l15;
                s16x8 kb = *reinterpret_cast<const s16x8*>(
                    &Ks[buf][trow * 64 + ((((kk >> 3) + g) ^ (trow & 7)) * 8)]);
                sc[tj] = __builtin_amdgcn_mfma_f32_16x16x32_bf16(kb, qa, sc[tj], 0, 0, 0);
            }
        }

        #pragma unroll
        for (int tj = 0; tj < 4; ++tj)
            #pragma unroll
            for (int i = 0; i < 4; ++i) {
                float p = exp2f(fminf(sc[tj][i], 60.f));
                sc[tj][i] = p;
                lsum += p;
            }

        #pragma unroll
        for (int tj = 0; tj < 4; ++tj) {
            u16x4 pk = { f2bf(sc[tj][0]), f2bf(sc[tj][1]), f2bf(sc[tj][2]), f2bf(sc[tj][3]) };
            *reinterpret_cast<u16x4*>(
                &Ps[w][l15 * 64 + (((tj * 2 + (g >> 1)) ^ (l15 & 7)) * 8) + (g & 1) * 4]) = pk;
        }

        #pragma unroll
        for (int kk = 0; kk < 64; kk += 32) {
            s16x8 pa = *reinterpret_cast<const s16x8*>(
                &Ps[w][l15 * 64 + ((((kk >> 3) + g) ^ (l15 & 7)) * 8)]);
            #pragma unroll
            for (int nj = 0; nj < 4; ++nj) {
                int d = nj * 16 + l15;
                s16x8 vb = *reinterpret_cast<const s16x8*>(
                    &Vt[buf][d * 64 + ((((kk >> 3) + g) ^ (d & 7)) * 8)]);
                ctxa[nj] = __builtin_amdgcn_mfma_f32_16x16x32_bf16(pa, vb, ctxa[nj], 0, 0, 0);
            }
        }
        buf ^= 1;
    }

    lsum += __shfl_xor(lsum, 16);
    lsum += __shfl_xor(lsum, 32);
    float invl = 1.0f / lsum;
    if (g == 0)
        ml[(size_t)(b * 16 + h) * 1024 + q0 + w * 16 + l15] = invl * 0.0625f;

    float invl_i[4];
    #pragma unroll
    for (int i = 0; i < 4; ++i) invl_i[i] = __shfl(invl, g * 4 + i);

    #pragma unroll
    for (int i = 0; i < 4; ++i) {
        int row = q0 + w * 16 + g * 4 + i;
        #pragma unroll
        for (int nj = 0; nj < 4; ++nj) {
            int d = nj * 16 + l15;
            ctx[(size_t)(b * 1024 + row) * 1024 + h * 64 + d] = f2bf(ctxa[nj][i] * invl_i[i]);
        }
    }
}

// ---------------- attn_weights = mean over heads of softmax(QK^T) ----------------
// R5-proven structure: 1 head per barrier, SCALAR prefetch regs (rule #20: no
// conditionally-filled register arrays -> no scratch spill).  ml pre-scaled 1/16.
__global__ __launch_bounds__(256, 4) void k_attnw(const u16* __restrict__ qk,
                                                  const float* __restrict__ ml,
                                                  float* __restrict__ attnw) {
    const int tt = blockIdx.x, st = blockIdx.y, b = blockIdx.z;
    const int s0 = st * 64, t0 = tt * 64;
    const int tid = threadIdx.x, lane = tid & 63, w = tid >> 6;
    const int g = lane >> 4, l15 = lane & 15;
    __shared__ __attribute__((aligned(16))) u16 Ks[2][64 * 64];
    __shared__ float mls[16][64];   // invl/16

    #pragma unroll
    for (int r = 0; r < 4; ++r) {
        int idx = tid + r * 256;
        int hh = idx >> 6, row = idx & 63;
        mls[hh][row] = ml[(size_t)(b * 16 + hh) * 1024 + s0 + row];
    }

    const int cA = tid, cB = tid + 256;
    const int rowA = cA >> 3, jA = cA & 7, rowB = cB >> 3, jB = cB & 7;
    const u16* kbase = qk + (size_t)(b * 1024 + t0) * 2048 + 1024;
    const size_t rowQbase = (size_t)(b * 1024 + s0 + w * 16 + l15) * 2048;

    __builtin_amdgcn_global_load_lds((AS1 const void*)(kbase + (size_t)rowA * 2048 + ((jA ^ (rowA & 7)) * 8)),
                                     (AS3 void*)(&Ks[0][cA * 8]), 16, 0, 0);
    __builtin_amdgcn_global_load_lds((AS1 const void*)(kbase + (size_t)rowB * 2048 + ((jB ^ (rowB & 7)) * 8)),
                                     (AS3 void*)(&Ks[0][cB * 8]), 16, 0, 0);
    s16x8 qc0 = *reinterpret_cast<const s16x8*>(qk + rowQbase + g * 8);
    s16x8 qc1 = *reinterpret_cast<const s16x8*>(qk + rowQbase + 32 + g * 8);

    f32x4 acc[4];
    #pragma unroll
    for (int tj = 0; tj < 4; ++tj) acc[tj] = (f32x4){0.f, 0.f, 0.f, 0.f};

    int buf = 0;
    for (int h = 0; h < 16; ++h) {
        __syncthreads();
        s16x8 qn0, qn1;
        if (h < 15) {
            const u16* kb2 = kbase + (h + 1) * 64;
            __builtin_amdgcn_global_load_lds((AS1 const void*)(kb2 + (size_t)rowA * 2048 + ((jA ^ (rowA & 7)) * 8)),
                                             (AS3 void*)(&Ks[buf ^ 1][cA * 8]), 16, 0, 0);
            __builtin_amdgcn_global_load_lds((AS1 const void*)(kb2 + (size_t)rowB * 2048 + ((jB ^ (rowB & 7)) * 8)),
                                             (AS3 void*)(&Ks[buf ^ 1][cB * 8]), 16, 0, 0);
            qn0 = *reinterpret_cast<const s16x8*>(qk + rowQbase + (h + 1) * 64 + g * 8);
            qn1 = *reinterpret_cast<const s16x8*>(qk + rowQbase + (h + 1) * 64 + 32 + g * 8);
        }

        f32x4 sc[4];
        #pragma unroll
        for (int tj = 0; tj < 4; ++tj) sc[tj] = (f32x4){0.f, 0.f, 0.f, 0.f};
        #pragma unroll
        for (int kk = 0; kk < 64; kk += 32) {
            s16x8 qa = kk ? qc1 : qc0;
            #pragma unroll
            for (int tj = 0; tj < 4; ++tj) {
                int trow = tj * 16 + l15;
                s16x8 kb = *reinterpret_cast<const s16x8*>(
                    &Ks[buf][trow * 64 + ((((kk >> 3) + g) ^ (trow & 7)) * 8)]);
                sc[tj] = __builtin_amdgcn_mfma_f32_16x16x32_bf16(qa, kb, sc[tj], 0, 0, 0);
            }
        }
        #pragma unroll
        for (int i = 0; i < 4; ++i) {
            int row = w * 16 + g * 4 + i;
            float M = mls[h][row];
            #pragma unroll
            for (int tj = 0; tj < 4; ++tj)
                acc[tj][i] += exp2f(fminf(sc[tj][i], 60.f)) * M;
        }
        qc0 = qn0; qc1 = qn1;
        buf ^= 1;
    }

    #pragma unroll
    for (int i = 0; i < 4; ++i) {
        int row = s0 + w * 16 + g * 4 + i;
        #pragma unroll
        for (int tj = 0; tj < 4; ++tj)
            attnw[(size_t)(b * 1024 + row) * 1024 + t0 + tj * 16 + l15] = acc[tj][i];
    }
}

// ---------------- launch ----------------
extern "C" void kernel_launch(void* const* d_in, const int* in_sizes, int n_in,
                              void* d_out, int out_size, void* d_ws, size_t ws_size,
                              hipStream_t stream) {
    const float* lstm = (const float*)d_in[0];   // [4,1024,1024]
    const float* wqkv = (const float*)d_in[1];   // [3072,1024]
    const float* bqkv = (const float*)d_in[2];   // [3072]
    const float* wout = (const float*)d_in[3];   // [1024,1024]
    const float* bout = (const float*)d_in[4];   // [1024]
    float* out = (float*)d_out;                  // [4096 ctxvec | 4*1024*1024 attn]

    char* ws = (char*)d_ws;
    u16*   Xbf   = (u16*)(ws);                          // 8 MiB
    u16*   Wqkvb = (u16*)(ws + 8u  * 1024 * 1024);      // 6 MiB
    u16*   Woutb = (u16*)(ws + 14u * 1024 * 1024);      // 2 MiB
    u16*   qkbuf = (u16*)(ws + 16u * 1024 * 1024);      // 16 MiB  [4096][2048]
    u16*   ctx   = (u16*)(ws + 32u * 1024 * 1024);      // 8 MiB
    u16*   vtg   = (u16*)(ws + 40u * 1024 * 1024);      // 8 MiB   [64][64][1024]
    float* ml    = (float*)(ws + 48u * 1024 * 1024);    // 256 KiB (invl/16)

    k_prep<<<8192, 256, 0, stream>>>(lstm, wqkv, wout, bout, Xbf, Wqkvb, Woutb, out);

    k_gemm_bt<0><<<dim3(24, 32), 256, 0, stream>>>(Xbf, Wqkvb, bqkv, qkbuf, vtg, nullptr);
    k_flash<<<dim3(16, 16, 4), 256, 0, stream>>>(qkbuf, vtg, ctx, ml);
    k_attnw<<<dim3(16, 16, 4), 256, 0, stream>>>(qkbuf, ml, out + 4096);
    k_gemm_bt<1><<<dim3(8, 32, 4), 256, 0, stream>>>(ctx, Woutb, nullptr, nullptr, nullptr, out);
}